// Round 2
// baseline (1048.965 us; speedup 1.0000x reference)
//
#include <hip/hip_runtime.h>
#include <hip/hip_bf16.h>

typedef __attribute__((ext_vector_type(8))) short bf16x8;
typedef __attribute__((ext_vector_type(4))) float f32x4;
typedef unsigned int uint32;
typedef unsigned short ushort;

#define MFMA16(a, b, c) __builtin_amdgcn_mfma_f32_16x16x32_bf16((a), (b), (c), 0, 0, 0)

__device__ __forceinline__ ushort f2bf(float f) {
    __hip_bfloat16 h = __float2bfloat16(f);
    return __builtin_bit_cast(ushort, h);
}
__device__ __forceinline__ float bf2f(ushort u) {
    uint32 v = ((uint32)u) << 16;
    return __builtin_bit_cast(float, v);
}

// ---------------------------------------------------------------------------
// Kernel 1a: transpose fp32 [C=256][N=4096] -> bf16 hi/lo [N][C]
// grid (N/64, C/64, 2*B), block 256
// ---------------------------------------------------------------------------
__global__ __launch_bounds__(256) void transpose_split(
    const float* __restrict__ Fc, const float* __restrict__ Fs,
    ushort* __restrict__ XcH, ushort* __restrict__ XcL,
    ushort* __restrict__ XsH, ushort* __restrict__ XsL) {
    __shared__ float lds[64][65];
    const int z = blockIdx.z;
    const int b = z & 3;
    const float* src = (z < 4) ? Fc : Fs;
    ushort* dh = (z < 4) ? XcH : XsH;
    ushort* dl = (z < 4) ? XcL : XsL;
    src += (size_t)b * 256 * 4096;
    dh += (size_t)b * 4096 * 256;
    dl += (size_t)b * 4096 * 256;
    const int i0 = blockIdx.x * 64;
    const int c0 = blockIdx.y * 64;
    const int col = threadIdx.x & 63;
    const int rb = threadIdx.x >> 6;  // 0..3
#pragma unroll
    for (int rr = 0; rr < 16; rr++) {
        int r = rb * 16 + rr;  // c-local
        lds[r][col] = src[(size_t)(c0 + r) * 4096 + i0 + col];
    }
    __syncthreads();
#pragma unroll
    for (int rr = 0; rr < 16; rr++) {
        int r = rb * 16 + rr;  // i-local
        float f = lds[col][r];
        ushort h = f2bf(f);
        dh[(size_t)(i0 + r) * 256 + c0 + col] = h;
        dl[(size_t)(i0 + r) * 256 + c0 + col] = f2bf(f - bf2f(h));
    }
}

// ---------------------------------------------------------------------------
// Kernel 1b: weights fp32 -> bf16; w_f scaled by log2e, w_f/w_g split hi/lo.
// grid 256, block 256
// ---------------------------------------------------------------------------
__global__ __launch_bounds__(256) void convert_weights(
    const float* __restrict__ wf, const float* __restrict__ wg,
    const float* __restrict__ wh, const float* __restrict__ wo,
    ushort* __restrict__ wfh, ushort* __restrict__ wfl,
    ushort* __restrict__ wgh, ushort* __restrict__ wgl,
    ushort* __restrict__ whb, ushort* __restrict__ wob) {
    const int t = blockIdx.x * 256 + threadIdx.x;  // 0..65535
    const float L2E = 1.4426950408889634f;
    float sf = wf[t] * L2E;
    ushort hf = f2bf(sf);
    wfh[t] = hf;
    wfl[t] = f2bf(sf - bf2f(hf));
    float sg = wg[t];
    ushort hg = f2bf(sg);
    wgh[t] = hg;
    wgl[t] = f2bf(sg - bf2f(hg));
    whb[t] = f2bf(wh[t]);
    wob[t] = f2bf(wo[t]);
}

// ---------------------------------------------------------------------------
// Kernel 2a: Q/K projection, split precision. NT GEMM, K=256.
//   Q: Qt[i,o] = Xc[i,:]·(L2E*wf)[o,:] + L2E*bf   (hi/lo out)
//   K: Kt[j,o] = Xs[j,:]·wg[o,:] + bg             (hi/lo out)
// grid (256, 8), block 256 (4 waves, tile 64x64, wave = 16m x 64n)
// ---------------------------------------------------------------------------
__global__ __launch_bounds__(256) void proj_qk(
    const ushort* __restrict__ XcH, const ushort* __restrict__ XcL,
    const ushort* __restrict__ XsH, const ushort* __restrict__ XsL,
    const ushort* __restrict__ wfh, const ushort* __restrict__ wfl,
    const ushort* __restrict__ wgh, const ushort* __restrict__ wgl,
    const float* __restrict__ bf_, const float* __restrict__ bg_,
    ushort* __restrict__ QH, ushort* __restrict__ QL,
    ushort* __restrict__ KH, ushort* __restrict__ KL) {
    const int y = blockIdx.y;
    const int isK = y >> 2;
    const int b = y & 3;
    const size_t bNC = (size_t)b * 4096 * 256;
    const ushort* Ah = (isK ? XsH : XcH) + bNC;
    const ushort* Al = (isK ? XsL : XcL) + bNC;
    const ushort* Bh = isK ? wgh : wfh;
    const ushort* Bl = isK ? wgl : wfl;
    const float* bias = isK ? bg_ : bf_;
    const float bscale = isK ? 1.0f : 1.4426950408889634f;
    ushort* Ch = (isK ? KH : QH) + bNC;
    ushort* Cl = (isK ? KL : QL) + bNC;
    const int m0 = (blockIdx.x & 63) * 64, n0 = (blockIdx.x >> 6) * 64;
    const int l = threadIdx.x & 63, wv = threadIdx.x >> 6;
    const int g = l >> 4, l15 = l & 15;
    const int mrow = m0 + wv * 16 + l15;

    f32x4 acc[4] = {{0, 0, 0, 0}, {0, 0, 0, 0}, {0, 0, 0, 0}, {0, 0, 0, 0}};
#pragma unroll
    for (int kk = 0; kk < 8; kk++) {
        bf16x8 ah = *(const bf16x8*)(Ah + (size_t)mrow * 256 + kk * 32 + g * 8);
        bf16x8 al = *(const bf16x8*)(Al + (size_t)mrow * 256 + kk * 32 + g * 8);
#pragma unroll
        for (int nt = 0; nt < 4; nt++) {
            const size_t boff = (size_t)(n0 + nt * 16 + l15) * 256 + kk * 32 + g * 8;
            bf16x8 bh = *(const bf16x8*)(Bh + boff);
            bf16x8 bl = *(const bf16x8*)(Bl + boff);
            acc[nt] = MFMA16(ah, bh, acc[nt]);
            acc[nt] = MFMA16(ah, bl, acc[nt]);
            acc[nt] = MFMA16(al, bh, acc[nt]);
        }
    }
#pragma unroll
    for (int nt = 0; nt < 4; nt++) {
        float bn = bias[n0 + nt * 16 + l15] * bscale;
#pragma unroll
        for (int r = 0; r < 4; r++) {
            int mr = m0 + wv * 16 + g * 4 + r;
            float v = acc[nt][r] + bn;
            ushort h = f2bf(v);
            Ch[(size_t)mr * 256 + n0 + nt * 16 + l15] = h;
            Cl[(size_t)mr * 256 + n0 + nt * 16 + l15] = f2bf(v - bf2f(h));
        }
    }
}

// ---------------------------------------------------------------------------
// Kernel 2b: V projection. V[o,j] = wh[o,:]·Xs[j,:] + bh[o], ldc=4096.
// grid (256, 4), block 256
// ---------------------------------------------------------------------------
__global__ __launch_bounds__(256) void proj_v(
    const ushort* __restrict__ XsH, const ushort* __restrict__ whb,
    const float* __restrict__ bh_, ushort* __restrict__ Vv) {
    const int b = blockIdx.y;
    const size_t bNC = (size_t)b * 4096 * 256;
    const ushort* A = whb;
    const ushort* Bp = XsH + bNC;
    ushort* Cp = Vv + bNC;
    const int m0 = (blockIdx.x & 3) * 64, n0 = (blockIdx.x >> 2) * 64;
    const int l = threadIdx.x & 63, wv = threadIdx.x >> 6;
    const int g = l >> 4, l15 = l & 15;
    const int mrow = m0 + wv * 16 + l15;

    f32x4 acc[4] = {{0, 0, 0, 0}, {0, 0, 0, 0}, {0, 0, 0, 0}, {0, 0, 0, 0}};
#pragma unroll
    for (int kk = 0; kk < 8; kk++) {
        bf16x8 af = *(const bf16x8*)(A + (size_t)mrow * 256 + kk * 32 + g * 8);
#pragma unroll
        for (int nt = 0; nt < 4; nt++) {
            bf16x8 bfr = *(const bf16x8*)(Bp + (size_t)(n0 + nt * 16 + l15) * 256 + kk * 32 + g * 8);
            acc[nt] = MFMA16(af, bfr, acc[nt]);
        }
    }
#pragma unroll
    for (int nt = 0; nt < 4; nt++) {
#pragma unroll
        for (int r = 0; r < 4; r++) {
            int mr = m0 + wv * 16 + g * 4 + r;
            Cp[(size_t)mr * 4096 + n0 + nt * 16 + l15] = f2bf(acc[nt][r] + bh_[mr]);
        }
    }
}

// ---------------------------------------------------------------------------
// Kernel 3: flash attention, split-precision QK^T.
// grid (N/64, B), block 256 (4 waves x 16 queries).
// Swapped QK^T: S^T[j][i] = mfma(K-frag(m=j), Q-frag(n=i)), 3-term hi/lo.
// Logits pre-scaled by log2e -> exp2 softmax.
// ---------------------------------------------------------------------------
__global__ __launch_bounds__(256) void attn(
    const ushort* __restrict__ QH, const ushort* __restrict__ QL,
    const ushort* __restrict__ KH, const ushort* __restrict__ KL,
    const ushort* __restrict__ Vv, ushort* __restrict__ Rt) {
    const int b = blockIdx.y;
    const int l = threadIdx.x & 63, wv = threadIdx.x >> 6;
    const int g = l >> 4, l15 = l & 15;
    const int iw = blockIdx.x * 64 + wv * 16;
    const ushort* QHb = QH + ((size_t)b * 4096 + iw) * 256;
    const ushort* QLb = QL + ((size_t)b * 4096 + iw) * 256;
    const ushort* KHb = KH + (size_t)b * 4096 * 256;
    const ushort* KLb = KL + (size_t)b * 4096 * 256;
    const ushort* Vb = Vv + (size_t)b * 4096 * 256;  // [256][4096]

    bf16x8 qh[8], ql[8];
#pragma unroll
    for (int kk = 0; kk < 8; kk++) {
        qh[kk] = *(const bf16x8*)(QHb + (size_t)l15 * 256 + kk * 32 + g * 8);
        ql[kk] = *(const bf16x8*)(QLb + (size_t)l15 * 256 + kk * 32 + g * 8);
    }

    f32x4 acc[16];
#pragma unroll
    for (int ct = 0; ct < 16; ct++) acc[ct] = (f32x4){0, 0, 0, 0};
    float M = -INFINITY, Lsum = 0.0f;

    for (int j0 = 0; j0 < 4096; j0 += 32) {
        f32x4 s0 = {0, 0, 0, 0}, s1 = {0, 0, 0, 0};
#pragma unroll
        for (int kk = 0; kk < 8; kk++) {
            const size_t o0 = (size_t)(j0 + l15) * 256 + kk * 32 + g * 8;
            const size_t o1 = (size_t)(j0 + 16 + l15) * 256 + kk * 32 + g * 8;
            bf16x8 kh0 = *(const bf16x8*)(KHb + o0);
            bf16x8 kh1 = *(const bf16x8*)(KHb + o1);
            bf16x8 kl0 = *(const bf16x8*)(KLb + o0);
            bf16x8 kl1 = *(const bf16x8*)(KLb + o1);
            s0 = MFMA16(kh0, qh[kk], s0);
            s0 = MFMA16(kh0, ql[kk], s0);
            s0 = MFMA16(kl0, qh[kk], s0);
            s1 = MFMA16(kh1, qh[kk], s1);
            s1 = MFMA16(kh1, ql[kk], s1);
            s1 = MFMA16(kl1, qh[kk], s1);
        }
        // lane holds S^T: query i = iw+l15; j = j0 + 16*t + g*4 + r
        float tm = fmaxf(fmaxf(fmaxf(s0[0], s0[1]), fmaxf(s0[2], s0[3])),
                         fmaxf(fmaxf(s1[0], s1[1]), fmaxf(s1[2], s1[3])));
        tm = fmaxf(tm, __shfl_xor(tm, 16));
        tm = fmaxf(tm, __shfl_xor(tm, 32));
        float newM = fmaxf(M, tm);
        if (__any(newM > M)) {
            float alpha = exp2f(M - newM);  // 1 if unchanged; 0 on first tile
            Lsum *= alpha;
            float ar[4];
#pragma unroll
            for (int r = 0; r < 4; r++) ar[r] = __shfl(alpha, g * 4 + r);
#pragma unroll
            for (int ct = 0; ct < 16; ct++) {
#pragma unroll
                for (int r = 0; r < 4; r++) acc[ct][r] *= ar[r];
            }
        }
        M = newM;
        float p[8];
#pragma unroll
        for (int r = 0; r < 4; r++) {
            p[r] = exp2f(s0[r] - M);
            p[4 + r] = exp2f(s1[r] - M);
        }
        Lsum += p[0] + p[1] + p[2] + p[3] + p[4] + p[5] + p[6] + p[7];

        uint32 pk[4];
        pk[0] = (uint32)f2bf(p[0]) | ((uint32)f2bf(p[1]) << 16);  // s0, j+{0,1}
        pk[1] = (uint32)f2bf(p[2]) | ((uint32)f2bf(p[3]) << 16);  // s0, j+{2,3}
        pk[2] = (uint32)f2bf(p[4]) | ((uint32)f2bf(p[5]) << 16);  // s1, j+{0,1}
        pk[3] = (uint32)f2bf(p[6]) | ((uint32)f2bf(p[7]) << 16);  // s1, j+{2,3}
        // gather PV A-fragment: lane (g,l15) needs P[i=l15][j = j0 + g*8 + 0..7]
        const int ts = g >> 1;
        const int s1l = l15 + ((g & 1) << 5);
        uint32 w0a = __shfl(pk[0], s1l), w0b = __shfl(pk[2], s1l);
        uint32 w1a = __shfl(pk[1], s1l), w1b = __shfl(pk[3], s1l);
        uint32 w2a = __shfl(pk[0], s1l + 16), w2b = __shfl(pk[2], s1l + 16);
        uint32 w3a = __shfl(pk[1], s1l + 16), w3b = __shfl(pk[3], s1l + 16);
        union { uint32 u[4]; bf16x8 v; } pun;
        pun.u[0] = ts ? w0b : w0a;
        pun.u[1] = ts ? w1b : w1a;
        pun.u[2] = ts ? w2b : w2a;
        pun.u[3] = ts ? w3b : w3a;
        bf16x8 pf = pun.v;

#pragma unroll
        for (int ct = 0; ct < 16; ct++) {
            bf16x8 vf = *(const bf16x8*)(Vb + (size_t)(ct * 16 + l15) * 4096 + j0 + g * 8);
            acc[ct] = MFMA16(pf, vf, acc[ct]);
        }
    }
    float Lt = Lsum + __shfl_xor(Lsum, 16);
    Lt += __shfl_xor(Lt, 32);
    float inv = 1.0f / Lt;
    float ivr[4];
#pragma unroll
    for (int r = 0; r < 4; r++) ivr[r] = __shfl(inv, g * 4 + r);
    ushort* Rb = Rt + ((size_t)b * 4096 + iw) * 256;
#pragma unroll
    for (int ct = 0; ct < 16; ct++) {
#pragma unroll
        for (int r = 0; r < 4; r++)
            Rb[(size_t)(g * 4 + r) * 256 + ct * 16 + l15] = f2bf(acc[ct][r] * ivr[r]);
    }
}

// ---------------------------------------------------------------------------
// Kernel 4: out[o,i] = wo[o,:]·Rt[i,:] + bo[o], fp32 out [C][N].
// grid (256, B), block 256
// ---------------------------------------------------------------------------
__global__ __launch_bounds__(256) void out_proj(
    const ushort* __restrict__ wob, const ushort* __restrict__ Rt,
    const float* __restrict__ bo, float* __restrict__ Out) {
    const int b = blockIdx.y;
    const int m0 = (blockIdx.x & 3) * 64;
    const int n0 = (blockIdx.x >> 2) * 64;
    const int l = threadIdx.x & 63, wv = threadIdx.x >> 6;
    const int g = l >> 4, l15 = l & 15;
    const ushort* Bp = Rt + (size_t)b * 4096 * 256;
    float* Ob = Out + (size_t)b * 256 * 4096;
    const int mrow = m0 + wv * 16 + l15;

    f32x4 acc[4] = {{0, 0, 0, 0}, {0, 0, 0, 0}, {0, 0, 0, 0}, {0, 0, 0, 0}};
#pragma unroll
    for (int kk = 0; kk < 8; kk++) {
        bf16x8 af = *(const bf16x8*)(wob + (size_t)mrow * 256 + kk * 32 + g * 8);
#pragma unroll
        for (int nt = 0; nt < 4; nt++) {
            bf16x8 bfr = *(const bf16x8*)(Bp + (size_t)(n0 + nt * 16 + l15) * 256 + kk * 32 + g * 8);
            acc[nt] = MFMA16(af, bfr, acc[nt]);
        }
    }
#pragma unroll
    for (int nt = 0; nt < 4; nt++) {
#pragma unroll
        for (int r = 0; r < 4; r++) {
            int mr = m0 + wv * 16 + g * 4 + r;
            Ob[(size_t)mr * 4096 + n0 + nt * 16 + l15] = acc[nt][r] + bo[mr];
        }
    }
}

// ---------------------------------------------------------------------------
extern "C" void kernel_launch(void* const* d_in, const int* in_sizes, int n_in,
                              void* d_out, int out_size, void* d_ws, size_t ws_size,
                              hipStream_t stream) {
    const float* Fc = (const float*)d_in[0];
    const float* Fs = (const float*)d_in[1];
    const float* wf = (const float*)d_in[2];
    const float* bf_ = (const float*)d_in[3];
    const float* wg = (const float*)d_in[4];
    const float* bg = (const float*)d_in[5];
    const float* wh = (const float*)d_in[6];
    const float* bh = (const float*)d_in[7];
    const float* wo = (const float*)d_in[8];
    const float* bo = (const float*)d_in[9];
    float* Out = (float*)d_out;

    char* ws = (char*)d_ws;
    const size_t SZ = (size_t)4 * 4096 * 256 * 2;  // 8 MB per [B][4096][256] bf16
    ushort* XcH = (ushort*)(ws + 0 * SZ);
    ushort* XcL = (ushort*)(ws + 1 * SZ);
    ushort* XsH = (ushort*)(ws + 2 * SZ);
    ushort* XsL = (ushort*)(ws + 3 * SZ);
    ushort* QHp = (ushort*)(ws + 4 * SZ);
    ushort* QLp = (ushort*)(ws + 5 * SZ);
    ushort* KHp = (ushort*)(ws + 6 * SZ);
    ushort* KLp = (ushort*)(ws + 7 * SZ);
    ushort* Vv  = (ushort*)(ws + 8 * SZ);
    char* wsw = ws + 9 * SZ;
    ushort* wfh = (ushort*)(wsw + 0 * 131072);
    ushort* wfl = (ushort*)(wsw + 1 * 131072);
    ushort* wgh = (ushort*)(wsw + 2 * 131072);
    ushort* wgl = (ushort*)(wsw + 3 * 131072);
    ushort* whb = (ushort*)(wsw + 4 * 131072);
    ushort* wob = (ushort*)(wsw + 5 * 131072);
    ushort* Rt = XcH;  // alias: XcH/XcL dead once Q is built

    transpose_split<<<dim3(64, 4, 8), 256, 0, stream>>>(Fc, Fs, XcH, XcL, XsH, XsL);
    convert_weights<<<dim3(256), 256, 0, stream>>>(wf, wg, wh, wo, wfh, wfl, wgh, wgl, whb, wob);
    proj_qk<<<dim3(256, 8), 256, 0, stream>>>(XcH, XcL, XsH, XsL, wfh, wfl, wgh, wgl,
                                              bf_, bg, QHp, QLp, KHp, KLp);
    proj_v<<<dim3(256, 4), 256, 0, stream>>>(XsH, whb, bh, Vv);
    attn<<<dim3(64, 4), 256, 0, stream>>>(QHp, QLp, KHp, KLp, Vv, Rt);
    out_proj<<<dim3(256, 4), 256, 0, stream>>>(wob, Rt, bo, Out);
}